// Round 1
// baseline (368.660 us; speedup 1.0000x reference)
//
#include <hip/hip_runtime.h>

#define PYR 40000
#define N_PV 2100
#define N_OLM 1800
#define N_BIST 1200
#define N_SEPT 100

// ws layout (floats)
#define WS_PV_RAW   0        // [2100]
#define WS_OLM_RAW  2100     // [1800]
#define WS_BIST_RAW 3900     // [1200]
#define WS_PV_LAT   5100     // [2100]
#define WS_OLM_IPV  7200     // [2100]
#define WS_GAP      9300     // [2100]
#define WS_OLM_GINH 11400    // [1800]
#define WS_SCAL     13200    // [0]=ext_mean [1]=gain

// out layout (floats)
#define O_PERI 0
#define O_GABA 40000
#define O_DEND 80000
#define O_OLMD 120000
#define O_PVS  160000
#define O_OLMS 162100
#define O_BIS  163900

__device__ __forceinline__ float wave_reduce(float acc) {
    #pragma unroll
    for (int o = 32; o > 0; o >>= 1) acc += __shfl_down(acc, o, 64);
    return acc;
}

// ---- Phase 1: big GEMVs over pyr spikes. One 256-thread block per output row.
__global__ __launch_bounds__(256) void k_phase1(
    const float* __restrict__ Wpv, const float* __restrict__ Wolm,
    const float* __restrict__ Wbi, const int* __restrict__ pyr,
    float* __restrict__ ws)
{
    int b = blockIdx.x;
    const float* W;
    float* dst;
    if (b < N_PV)               { W = Wpv  + (size_t)b * PYR;                 dst = ws + WS_PV_RAW  + b; }
    else if (b < N_PV + N_OLM)  { int r = b - N_PV;         W = Wolm + (size_t)r * PYR; dst = ws + WS_OLM_RAW  + r; }
    else                        { int r = b - N_PV - N_OLM; W = Wbi  + (size_t)r * PYR; dst = ws + WS_BIST_RAW + r; }

    const float4* W4 = (const float4*)W;
    const int4*   S4 = (const int4*)pyr;
    float acc = 0.0f;
    for (int j = threadIdx.x; j < PYR / 4; j += 256) {
        float4 w = W4[j];
        int4   s = S4[j];
        acc += w.x * (float)s.x + w.y * (float)s.y + w.z * (float)s.z + w.w * (float)s.w;
    }
    acc = wave_reduce(acc);
    __shared__ float sm[4];
    int lane = threadIdx.x & 63, wv = threadIdx.x >> 6;
    if (lane == 0) sm[wv] = acc;
    __syncthreads();
    if (threadIdx.x == 0) *dst = sm[0] + sm[1] + sm[2] + sm[3];
}

// ---- Small GEMVs: wave-per-row.
__global__ __launch_bounds__(256) void k_small(
    const float* __restrict__ Wpvpv, const float* __restrict__ Wolmpv,
    const float* __restrict__ Wgap,  const float* __restrict__ Wsept,
    const float* __restrict__ prev_pv, const float* __restrict__ prev_olm,
    const float* __restrict__ prev_vm, const float* __restrict__ sept_g,
    float* __restrict__ ws)
{
    int r = blockIdx.x * 4 + (threadIdx.x >> 6);
    int lane = threadIdx.x & 63;
    const float* W; const float* v; int len4; float* dst;
    if (r < N_PV)                   { W = Wpvpv  + (size_t)r * N_PV;              v = prev_pv;  len4 = N_PV / 4;  dst = ws + WS_PV_LAT  + r; }
    else if (r < 2 * N_PV)          { int i = r - N_PV;     W = Wolmpv + (size_t)i * N_OLM;  v = prev_olm; len4 = N_OLM / 4; dst = ws + WS_OLM_IPV + i; }
    else if (r < 3 * N_PV)          { int i = r - 2 * N_PV; W = Wgap   + (size_t)i * N_PV;   v = prev_vm;  len4 = N_PV / 4;  dst = ws + WS_GAP     + i; }
    else if (r < 3 * N_PV + N_OLM)  { int i = r - 3 * N_PV; W = Wsept  + (size_t)i * N_SEPT; v = sept_g;   len4 = N_SEPT / 4; dst = ws + WS_OLM_GINH + i; }
    else return;

    const float4* W4 = (const float4*)W;
    const float4* V4 = (const float4*)v;
    float acc = 0.0f;
    for (int j = lane; j < len4; j += 64) {
        float4 w = W4[j], x = V4[j];
        acc += w.x * x.x + w.y * x.y + w.z * x.z + w.w * x.w;
    }
    acc = wave_reduce(acc);
    if (lane == 0) *dst = acc;
}

// ---- Scalars: ext_mean, drive -> gain
__global__ __launch_bounds__(256) void k_scal(const float* __restrict__ ext, float* __restrict__ ws)
{
    __shared__ float s1[256], s2[256];
    float a = 0.0f, b = 0.0f;
    for (int i = threadIdx.x; i < N_PV; i += 256) { a += ext[i]; b += ws[WS_PV_RAW + i]; }
    s1[threadIdx.x] = a; s2[threadIdx.x] = b;
    __syncthreads();
    for (int o = 128; o > 0; o >>= 1) {
        if (threadIdx.x < o) { s1[threadIdx.x] += s1[threadIdx.x + o]; s2[threadIdx.x] += s2[threadIdx.x + o]; }
        __syncthreads();
    }
    if (threadIdx.x == 0) {
        float ext_mean = s1[0] / (float)N_PV;
        float drive    = s2[0] / (float)N_PV;
        float gain = (drive > 0.01f) ? fminf(1.0f, drive / 0.1f) : 0.0f;
        ws[WS_SCAL]     = ext_mean;
        ws[WS_SCAL + 1] = gain;
    }
}

// ---- LIF step: one thread per interneuron, writes spike outputs.
__global__ __launch_bounds__(256) void k_lif(
    const float* __restrict__ ws,
    const float* __restrict__ pv_v,  const float* __restrict__ olm_v,  const float* __restrict__ bist_v,
    const float* __restrict__ pv_ad, const float* __restrict__ olm_ad, const float* __restrict__ bist_ad,
    float* __restrict__ out)
{
    int t = blockIdx.x * 256 + threadIdx.x;
    float ext_mean = ws[WS_SCAL], gain = ws[WS_SCAL + 1];
    if (t < N_PV) {
        float g = ws[WS_PV_RAW + t] + ext_mean * 0.3f
                - ws[WS_PV_LAT + t] * 0.5f - ws[WS_OLM_IPV + t] * 0.3f
                + ws[WS_GAP + t] * 0.05f * gain;
        g = fmaxf(g, 0.0f);
        float ga = g * 0.7f, gn = g * 0.3f;
        float v = pv_v[t], ad = pv_ad[t];
        float isyn = (ga + gn) * (3.0f - v);
        float vn = v + (1.0f / 7.0f) * (-v + isyn);
        out[O_PVS + t] = (vn >= 2.0f + ad) ? 1.0f : 0.0f;
    } else if (t < N_PV + N_OLM) {
        int i = t - N_PV;
        float g = ws[WS_OLM_RAW + i] + ext_mean * 0.1f;
        g = fmaxf(g, 0.0f);
        float ga = g * 0.7f, gn = g * 0.3f;
        float gi = ws[WS_OLM_GINH + i];
        float v = olm_v[i], ad = olm_ad[i];
        float isyn = (ga + gn) * (3.0f - v) + gi * (-0.5f - v);
        float vn = v + (1.0f / 25.0f) * (-v + isyn);
        out[O_OLMS + i] = (vn >= 1.1f + ad) ? 1.0f : 0.0f;
    } else if (t < N_PV + N_OLM + N_BIST) {
        int i = t - N_PV - N_OLM;
        float g = ws[WS_BIST_RAW + i] + ext_mean * 0.2f;
        g = fmaxf(g, 0.0f);
        float ga = g * 0.7f, gn = g * 0.3f;
        float v = bist_v[i], ad = bist_ad[i];
        float isyn = (ga + gn) * (3.0f - v);
        float vn = v + (1.0f / 12.0f) * (-v + isyn);
        out[O_BIS + i] = (vn >= 0.9f + ad) ? 1.0f : 0.0f;
    }
}

// ---- Phase 2: interneuron -> pyr GEMVs, wave-per-row over 4 matrices.
__global__ __launch_bounds__(256) void k_phase2(
    const float* __restrict__ Wpp, const float* __restrict__ Wppb,
    const float* __restrict__ Wop, const float* __restrict__ Wbp,
    float* __restrict__ out)
{
    int r = blockIdx.x * 4 + (threadIdx.x >> 6);  // 0 .. 160000-1
    int lane = threadIdx.x & 63;
    int job = r / PYR;
    int p = r - job * PYR;
    const float* W; const float* v; int len4; float* dst;
    if (job == 0)      { W = Wpp  + (size_t)p * N_PV;   v = out + O_PVS;  len4 = N_PV / 4;   dst = out + O_PERI + p; }
    else if (job == 1) { W = Wppb + (size_t)p * N_PV;   v = out + O_PVS;  len4 = N_PV / 4;   dst = out + O_GABA + p; }
    else if (job == 2) { W = Wop  + (size_t)p * N_OLM;  v = out + O_OLMS; len4 = N_OLM / 4;  dst = out + O_OLMD + p; }
    else               { W = Wbp  + (size_t)p * N_BIST; v = out + O_BIS;  len4 = N_BIST / 4; dst = out + O_DEND + p; }

    const float4* W4 = (const float4*)W;
    const float4* V4 = (const float4*)v;
    float acc = 0.0f;
    for (int j = lane; j < len4; j += 64) {
        float4 w = W4[j], x = V4[j];
        acc += w.x * x.x + w.y * x.y + w.z * x.z + w.w * x.w;
    }
    acc = wave_reduce(acc);
    if (lane == 0) *dst = acc;
}

// ---- dendritic = bist_part + olm_dendritic
__global__ __launch_bounds__(256) void k_add(float* __restrict__ out)
{
    int i = blockIdx.x * 256 + threadIdx.x;
    if (i < PYR) out[O_DEND + i] += out[O_OLMD + i];
}

extern "C" void kernel_launch(void* const* d_in, const int* in_sizes, int n_in,
                              void* d_out, int out_size, void* d_ws, size_t ws_size,
                              hipStream_t stream)
{
    const int*   pyr     = (const int*)  d_in[0];
    const float* sept_g  = (const float*)d_in[1];
    const float* ext     = (const float*)d_in[2];
    const float* prev_pv = (const float*)d_in[3];
    const float* prev_olm= (const float*)d_in[4];
    const float* prev_vm = (const float*)d_in[5];
    const float* pv_v    = (const float*)d_in[6];
    const float* olm_v   = (const float*)d_in[7];
    const float* bist_v  = (const float*)d_in[8];
    const float* pv_ad   = (const float*)d_in[9];
    const float* olm_ad  = (const float*)d_in[10];
    const float* bist_ad = (const float*)d_in[11];
    const float* Wpyr_pv = (const float*)d_in[12];
    const float* Wpyr_olm= (const float*)d_in[13];
    const float* Wpyr_bi = (const float*)d_in[14];
    const float* Wpp     = (const float*)d_in[15];
    const float* Wppb    = (const float*)d_in[16];
    const float* Wop     = (const float*)d_in[17];
    const float* Wbp     = (const float*)d_in[18];
    const float* Wpvpv   = (const float*)d_in[19];
    const float* Wolmpv  = (const float*)d_in[20];
    const float* Wgap    = (const float*)d_in[21];
    const float* Wsept   = (const float*)d_in[22];

    float* ws  = (float*)d_ws;
    float* out = (float*)d_out;

    k_phase1<<<N_PV + N_OLM + N_BIST, 256, 0, stream>>>(Wpyr_pv, Wpyr_olm, Wpyr_bi, pyr, ws);
    k_small<<<(3 * N_PV + N_OLM) / 4, 256, 0, stream>>>(Wpvpv, Wolmpv, Wgap, Wsept,
                                                        prev_pv, prev_olm, prev_vm, sept_g, ws);
    k_scal<<<1, 256, 0, stream>>>(ext, ws);
    k_lif<<<(N_PV + N_OLM + N_BIST + 255) / 256, 256, 0, stream>>>(
        ws, pv_v, olm_v, bist_v, pv_ad, olm_ad, bist_ad, out);
    k_phase2<<<(4 * PYR) / 4, 256, 0, stream>>>(Wpp, Wppb, Wop, Wbp, out);
    k_add<<<(PYR + 255) / 256, 256, 0, stream>>>(out);
}

// Round 2
// 334.211 us; speedup vs baseline: 1.1031x; 1.1031x over previous
//
#include <hip/hip_runtime.h>

#define PYR 40000
#define N_PV 2100
#define N_OLM 1800
#define N_BIST 1200
#define N_SEPT 100

// ws layout (floats)
#define WS_PV_RAW   0        // [2100]
#define WS_OLM_RAW  2100     // [1800]
#define WS_BIST_RAW 3900     // [1200]
#define WS_PV_LAT   5100     // [2100]
#define WS_OLM_IPV  7200     // [2100]
#define WS_GAP      9300     // [2100]
#define WS_OLM_GINH 11400    // [1800]

// out layout (floats)
#define O_PERI 0
#define O_GABA 40000
#define O_DEND 80000
#define O_OLMD 120000
#define O_PVS  160000
#define O_OLMS 162100
#define O_BIS  163900

typedef float f4 __attribute__((ext_vector_type(4)));
typedef int   i4 __attribute__((ext_vector_type(4)));

__device__ __forceinline__ f4 ntload(const f4* p) { return __builtin_nontemporal_load(p); }

__device__ __forceinline__ float wave_reduce(float acc) {
    #pragma unroll
    for (int o = 32; o > 0; o >>= 1) acc += __shfl_down(acc, o, 64);
    return acc;
}

// ---- Kernel 1: phase-1 big GEMVs (block-per-row) + small GEMVs (wave-per-row)
#define P1_BLOCKS (N_PV + N_OLM + N_BIST)                 // 5100
#define SMALL_BLOCKS ((3 * N_PV + N_OLM + 3) / 4)         // 2025
__global__ __launch_bounds__(256) void k_big(
    const float* __restrict__ Wpv, const float* __restrict__ Wolm,
    const float* __restrict__ Wbi, const int* __restrict__ pyr,
    const float* __restrict__ Wpvpv, const float* __restrict__ Wolmpv,
    const float* __restrict__ Wgap,  const float* __restrict__ Wsept,
    const float* __restrict__ prev_pv, const float* __restrict__ prev_olm,
    const float* __restrict__ prev_vm, const float* __restrict__ sept_g,
    float* __restrict__ ws)
{
    int b = blockIdx.x;
    if (b < P1_BLOCKS) {
        const float* W; float* dst;
        if (b < N_PV)               { W = Wpv  + (size_t)b * PYR;                   dst = ws + WS_PV_RAW  + b; }
        else if (b < N_PV + N_OLM)  { int r = b - N_PV;         W = Wolm + (size_t)r * PYR; dst = ws + WS_OLM_RAW  + r; }
        else                        { int r = b - N_PV - N_OLM; W = Wbi  + (size_t)r * PYR; dst = ws + WS_BIST_RAW + r; }

        const f4* W4 = (const f4*)W;
        const i4* S4 = (const i4*)pyr;
        float acc = 0.0f;
        for (int j = threadIdx.x; j < PYR / 4; j += 256) {
            f4 w = ntload(W4 + j);
            i4 s = S4[j];
            acc += w.x * (float)s.x + w.y * (float)s.y + w.z * (float)s.z + w.w * (float)s.w;
        }
        acc = wave_reduce(acc);
        __shared__ float sm[4];
        int lane = threadIdx.x & 63, wv = threadIdx.x >> 6;
        if (lane == 0) sm[wv] = acc;
        __syncthreads();
        if (threadIdx.x == 0) *dst = sm[0] + sm[1] + sm[2] + sm[3];
        return;
    }
    // small GEMVs
    int r = (b - P1_BLOCKS) * 4 + (threadIdx.x >> 6);
    int lane = threadIdx.x & 63;
    const float* W; const float* v; int len4; float* dst;
    if (r < N_PV)                   { W = Wpvpv  + (size_t)r * N_PV;               v = prev_pv;  len4 = N_PV / 4;   dst = ws + WS_PV_LAT  + r; }
    else if (r < 2 * N_PV)          { int i = r - N_PV;     W = Wolmpv + (size_t)i * N_OLM;  v = prev_olm; len4 = N_OLM / 4;  dst = ws + WS_OLM_IPV + i; }
    else if (r < 3 * N_PV)          { int i = r - 2 * N_PV; W = Wgap   + (size_t)i * N_PV;   v = prev_vm;  len4 = N_PV / 4;   dst = ws + WS_GAP     + i; }
    else if (r < 3 * N_PV + N_OLM)  { int i = r - 3 * N_PV; W = Wsept  + (size_t)i * N_SEPT; v = sept_g;   len4 = N_SEPT / 4; dst = ws + WS_OLM_GINH + i; }
    else return;

    const f4* W4 = (const f4*)W;
    const f4* V4 = (const f4*)v;
    float acc = 0.0f;
    for (int j = lane; j < len4; j += 64) {
        f4 w = ntload(W4 + j), x = V4[j];
        acc += w.x * x.x + w.y * x.y + w.z * x.z + w.w * x.w;
    }
    acc = wave_reduce(acc);
    if (lane == 0) *dst = acc;
}

// ---- Kernel 2: per-block redundant scalar reduce (ext_mean, drive->gain) + LIF
__global__ __launch_bounds__(256) void k_lif(
    const float* __restrict__ ws, const float* __restrict__ ext,
    const float* __restrict__ pv_v,  const float* __restrict__ olm_v,  const float* __restrict__ bist_v,
    const float* __restrict__ pv_ad, const float* __restrict__ olm_ad, const float* __restrict__ bist_ad,
    float* __restrict__ out)
{
    __shared__ float s1[256], s2[256];
    float a = 0.0f, bsum = 0.0f;
    for (int i = threadIdx.x; i < N_PV; i += 256) { a += ext[i]; bsum += ws[WS_PV_RAW + i]; }
    s1[threadIdx.x] = a; s2[threadIdx.x] = bsum;
    __syncthreads();
    for (int o = 128; o > 0; o >>= 1) {
        if (threadIdx.x < o) { s1[threadIdx.x] += s1[threadIdx.x + o]; s2[threadIdx.x] += s2[threadIdx.x + o]; }
        __syncthreads();
    }
    float ext_mean = s1[0] / (float)N_PV;
    float drive    = s2[0] / (float)N_PV;
    float gain = (drive > 0.01f) ? fminf(1.0f, drive / 0.1f) : 0.0f;

    int t = blockIdx.x * 256 + threadIdx.x;
    if (t < N_PV) {
        float g = ws[WS_PV_RAW + t] + ext_mean * 0.3f
                - ws[WS_PV_LAT + t] * 0.5f - ws[WS_OLM_IPV + t] * 0.3f
                + ws[WS_GAP + t] * 0.05f * gain;
        g = fmaxf(g, 0.0f);
        float v = pv_v[t], ad = pv_ad[t];
        float isyn = g * (3.0f - v);
        float vn = v + (1.0f / 7.0f) * (-v + isyn);
        out[O_PVS + t] = (vn >= 2.0f + ad) ? 1.0f : 0.0f;
    } else if (t < N_PV + N_OLM) {
        int i = t - N_PV;
        float g = fmaxf(ws[WS_OLM_RAW + i] + ext_mean * 0.1f, 0.0f);
        float gi = ws[WS_OLM_GINH + i];
        float v = olm_v[i], ad = olm_ad[i];
        float isyn = g * (3.0f - v) + gi * (-0.5f - v);
        float vn = v + (1.0f / 25.0f) * (-v + isyn);
        out[O_OLMS + i] = (vn >= 1.1f + ad) ? 1.0f : 0.0f;
    } else if (t < N_PV + N_OLM + N_BIST) {
        int i = t - N_PV - N_OLM;
        float g = fmaxf(ws[WS_BIST_RAW + i] + ext_mean * 0.2f, 0.0f);
        float v = bist_v[i], ad = bist_ad[i];
        float isyn = g * (3.0f - v);
        float vn = v + (1.0f / 12.0f) * (-v + isyn);
        out[O_BIS + i] = (vn >= 0.9f + ad) ? 1.0f : 0.0f;
    }
}

// ---- Kernel 3: phase-2 GEMVs, wave-per-row; olm+bist fused -> dendritic direct
__global__ __launch_bounds__(256) void k_phase2(
    const float* __restrict__ Wpp, const float* __restrict__ Wppb,
    const float* __restrict__ Wop, const float* __restrict__ Wbp,
    float* __restrict__ out)
{
    int r = blockIdx.x * 4 + (threadIdx.x >> 6);  // 0 .. 3*PYR-1
    int lane = threadIdx.x & 63;
    int job = r / PYR;
    int p = r - job * PYR;

    if (job < 2) {
        const float* W = (job == 0 ? Wpp : Wppb) + (size_t)p * N_PV;
        const f4* W4 = (const f4*)W;
        const f4* V4 = (const f4*)(out + O_PVS);
        float acc = 0.0f;
        for (int j = lane; j < N_PV / 4; j += 64) {
            f4 w = ntload(W4 + j), x = V4[j];
            acc += w.x * x.x + w.y * x.y + w.z * x.z + w.w * x.w;
        }
        acc = wave_reduce(acc);
        if (lane == 0) out[(job == 0 ? O_PERI : O_GABA) + p] = acc;
    } else {
        const f4* Wo4 = (const f4*)(Wop + (size_t)p * N_OLM);
        const f4* Wb4 = (const f4*)(Wbp + (size_t)p * N_BIST);
        const f4* Vo4 = (const f4*)(out + O_OLMS);
        const f4* Vb4 = (const f4*)(out + O_BIS);
        float ao = 0.0f, ab = 0.0f;
        for (int j = lane; j < N_OLM / 4; j += 64) {
            f4 w = ntload(Wo4 + j), x = Vo4[j];
            ao += w.x * x.x + w.y * x.y + w.z * x.z + w.w * x.w;
        }
        for (int j = lane; j < N_BIST / 4; j += 64) {
            f4 w = ntload(Wb4 + j), x = Vb4[j];
            ab += w.x * x.x + w.y * x.y + w.z * x.z + w.w * x.w;
        }
        ao = wave_reduce(ao);
        ab = wave_reduce(ab);
        if (lane == 0) {
            out[O_OLMD + p] = ao;
            out[O_DEND + p] = ao + ab;
        }
    }
}

extern "C" void kernel_launch(void* const* d_in, const int* in_sizes, int n_in,
                              void* d_out, int out_size, void* d_ws, size_t ws_size,
                              hipStream_t stream)
{
    const int*   pyr     = (const int*)  d_in[0];
    const float* sept_g  = (const float*)d_in[1];
    const float* ext     = (const float*)d_in[2];
    const float* prev_pv = (const float*)d_in[3];
    const float* prev_olm= (const float*)d_in[4];
    const float* prev_vm = (const float*)d_in[5];
    const float* pv_v    = (const float*)d_in[6];
    const float* olm_v   = (const float*)d_in[7];
    const float* bist_v  = (const float*)d_in[8];
    const float* pv_ad   = (const float*)d_in[9];
    const float* olm_ad  = (const float*)d_in[10];
    const float* bist_ad = (const float*)d_in[11];
    const float* Wpyr_pv = (const float*)d_in[12];
    const float* Wpyr_olm= (const float*)d_in[13];
    const float* Wpyr_bi = (const float*)d_in[14];
    const float* Wpp     = (const float*)d_in[15];
    const float* Wppb    = (const float*)d_in[16];
    const float* Wop     = (const float*)d_in[17];
    const float* Wbp     = (const float*)d_in[18];
    const float* Wpvpv   = (const float*)d_in[19];
    const float* Wolmpv  = (const float*)d_in[20];
    const float* Wgap    = (const float*)d_in[21];
    const float* Wsept   = (const float*)d_in[22];

    float* ws  = (float*)d_ws;
    float* out = (float*)d_out;

    k_big<<<P1_BLOCKS + SMALL_BLOCKS, 256, 0, stream>>>(
        Wpyr_pv, Wpyr_olm, Wpyr_bi, pyr,
        Wpvpv, Wolmpv, Wgap, Wsept,
        prev_pv, prev_olm, prev_vm, sept_g, ws);
    k_lif<<<(N_PV + N_OLM + N_BIST + 255) / 256, 256, 0, stream>>>(
        ws, ext, pv_v, olm_v, bist_v, pv_ad, olm_ad, bist_ad, out);
    k_phase2<<<(3 * PYR) / 4, 256, 0, stream>>>(Wpp, Wppb, Wop, Wbp, out);
}